// Round 9
// baseline (183.200 us; speedup 1.0000x reference)
//
#include <hip/hip_runtime.h>
#include <hip/hip_bf16.h>
#include <cstdint>

#define B_    4
#define LQ    1024
#define LK    2048
#define FEAT  11
#define SP_   8
#define WD_   3
#define H_    8
#define HID_  256
#define LOG2E 1.4426950408889634f
#define SPLIT 4
#define KPS   (LK / SPLIT)    // 512 k per split
#define ITERS (KPS / 64)      // 8 rounds of 64 k

typedef __attribute__((ext_vector_type(4))) float f32x4;
typedef __attribute__((ext_vector_type(8))) short bf16x8;
typedef __attribute__((ext_vector_type(4))) short s16x4;

__device__ __forceinline__ float sigmoidf_(float x) { return 1.f / (1.f + __expf(-x)); }

__device__ __forceinline__ short f2bf(float f) {
  unsigned u = __float_as_uint(f);
  u += 0x7fffu + ((u >> 16) & 1u);
  return (short)(u >> 16);
}
__device__ __forceinline__ float bf2f(short s) {
  return __uint_as_float(((unsigned)(unsigned short)s) << 16);
}

__device__ __forceinline__ void gl_lds16(const void* g, void* l) {
  __builtin_amdgcn_global_load_lds(
      (const __attribute__((address_space(1))) unsigned int*)g,
      (__attribute__((address_space(3))) unsigned int*)l, 16, 0, 0);
}

// ---------------------------------------------------------------------------
// Q projection -> Qh bf16 [bh][q][64]; scales (c1,c2) and log2e folded in.
// Block = (64-q tile, bh); thread (q_local = t>>2, part = t&3) computes
// 8 struct + 8 wave features -> x read 4x per row instead of 256x.
// ---------------------------------------------------------------------------
__global__ __launch_bounds__(256) void proj_q_kernel(
    const float* __restrict__ q_fp, const float* __restrict__ Wq_s,
    const float* __restrict__ bq_s, const float* __restrict__ Wq_w,
    const float* __restrict__ bq_w, const float* __restrict__ wb,
    short* __restrict__ Qh)
{
  const int blk = blockIdx.x, bh = blockIdx.y;
  const int b = bh >> 3, h = bh & 7;
  const int t = threadIdx.x;
  const int ql = t >> 2, part = t & 3;
  const int q = blk * 64 + ql;
  const float alpha = sigmoidf_(wb[0]);
  const float c1 = (1.f - alpha) * 0.17677669529663687f * LOG2E;
  const float c2 = 2.f * alpha * 10.f * LOG2E;

  const float* x = q_fp + (size_t)(b * LQ + q) * FEAT;
  float xs[FEAT];
  #pragma unroll
  for (int f = 0; f < FEAT; ++f) xs[f] = x[f];

  const size_t base = ((size_t)bh * LQ + q) * 64 + part * 8;
  s16x4 out_s[2], out_w[2];
  #pragma unroll
  for (int i = 0; i < 8; ++i) {
    const int dg = h * 32 + part * 8 + i;
    float s = bq_s[dg];
    #pragma unroll
    for (int f = 0; f < SP_; ++f) s += xs[f] * Wq_s[dg * SP_ + f];
    float w = bq_w[dg];
    #pragma unroll
    for (int f = 0; f < WD_; ++f) w += xs[SP_ + f] * Wq_w[dg * WD_ + f];
    out_s[i >> 2][i & 3] = f2bf(c1 * s);
    out_w[i >> 2][i & 3] = f2bf(c2 * w);
  }
  *(s16x4*)(Qh + base)          = out_s[0];
  *(s16x4*)(Qh + base + 4)      = out_s[1];
  *(s16x4*)(Qh + base + 32)     = out_w[0];
  *(s16x4*)(Qh + base + 36)     = out_w[1];
}

// ---------------------------------------------------------------------------
// Fused K/V projection + fragment prepack. Block = (64-k tile, bh).
// ---------------------------------------------------------------------------
__global__ __launch_bounds__(256) void projk_pack_kernel(
    const float* __restrict__ v_ret, const float* __restrict__ Wk_s,
    const float* __restrict__ bk_s, const float* __restrict__ Wk_w,
    const float* __restrict__ bk_w, const float* __restrict__ Wv,
    const float* __restrict__ bv,   const float* __restrict__ wb,
    short* __restrict__ KV, float* __restrict__ kb)
{
  __shared__ float ldsv[64][33];
  const int blk = blockIdx.x, bh = blockIdx.y;
  const int b = bh >> 3, h = bh & 7;
  const int t = threadIdx.x;
  const int kl = t >> 2, part = t & 3;
  const int k = blk * 64 + kl;
  const float alpha = sigmoidf_(wb[0]);

  const float* x = v_ret + (size_t)(b * LK + k) * FEAT;
  float xs[FEAT];
  #pragma unroll
  for (int f = 0; f < FEAT; ++f) xs[f] = x[f];

  float s8[8], w8[8], v8[8];
  #pragma unroll
  for (int i = 0; i < 8; ++i) {
    const int d = h * 32 + part * 8 + i;
    float s = bk_s[d];
    #pragma unroll
    for (int f = 0; f < SP_; ++f) s += xs[f] * Wk_s[d * SP_ + f];
    float w = bk_w[d];
    #pragma unroll
    for (int f = 0; f < WD_; ++f) w += xs[SP_ + f] * Wk_w[d * WD_ + f];
    float v = bv[d];
    #pragma unroll
    for (int f = 0; f < FEAT; ++f) v += xs[f] * Wv[d * FEAT + f];
    s8[i] = s; w8[i] = w; v8[i] = v;
    ldsv[kl][part * 8 + i] = v;
  }

  float sq = 0.f;
  #pragma unroll
  for (int i = 0; i < 8; ++i) sq += w8[i] * w8[i];
  sq += __shfl_xor(sq, 1);
  sq += __shfl_xor(sq, 2);
  if (part == 0) kb[(size_t)bh * LK + k] = -10.f * alpha * LOG2E * sq;

  const int a  = kl >> 5;
  const int bb = (kl >> 2) & 1;
  const int p  = kl - a * 32 - bb * 4;
  const int lo = ((p >> 3) << 2) | (p & 3);
  const int t4 = a * 2 + bb;
  const size_t base = ((size_t)bh * 32 + blk) * 768;

  bf16x8 hs, hw;
  #pragma unroll
  for (int i = 0; i < 8; ++i) { hs[i] = f2bf(s8[i]); hw[i] = f2bf(w8[i]); }
  *(bf16x8*)(KV + (base + (t4 * 2 + 0) * 64 + part * 16 + lo) * 8) = hs;
  *(bf16x8*)(KV + (base + (t4 * 2 + 1) * 64 + part * 16 + lo) * 8) = hw;

  __syncthreads();

  {
    const int j = t >> 6, l = t & 63;
    const int dt = j >> 1, kw = j & 1;
    const int lo2 = l & 15, quad = l >> 4;
    const int d = dt * 16 + lo2;
    bf16x8 hv;
    #pragma unroll
    for (int i = 0; i < 8; ++i)
      hv[i] = f2bf(ldsv[kw * 32 + quad * 8 + i][d]);
    *(bf16x8*)(KV + (base + 512 + t) * 8) = hv;
  }
}

// ---------------------------------------------------------------------------
// Flash attention: 32 q per wave (2 q-tiles share K/V LDS fragments),
// LDS double buffer via global_load_lds, log-free softmax, l via MFMA
// ones-row, SPLIT=4, XCD-swizzled 1-D grid. pi read DIRECTLY from the
// input tensor (structured 16-row gather; no prepack kernel).
// ---------------------------------------------------------------------------
union PF { int i[4]; bf16x8 v; };

__device__ __forceinline__ void attn_step2(
    const short* __restrict__ cbuf, const bf16x8 qh[2][2],
    const float* __restrict__ pib0, const float* __restrict__ pib1,
    const float* __restrict__ kbp, const bf16x8 ones, int lane,
    float m[2], f32x4 o[2][2], f32x4 ol[2])
{
  // pi (direct, fragment-addressed gather) + kb (quad-broadcast), issued first
  f32x4 pi4[2][4];
  pi4[0][0] = *(const f32x4*)(pib0);
  pi4[0][1] = *(const f32x4*)(pib0 + 4);
  pi4[0][2] = *(const f32x4*)(pib0 + 32);
  pi4[0][3] = *(const f32x4*)(pib0 + 36);
  pi4[1][0] = *(const f32x4*)(pib1);
  pi4[1][1] = *(const f32x4*)(pib1 + 4);
  pi4[1][2] = *(const f32x4*)(pib1 + 32);
  pi4[1][3] = *(const f32x4*)(pib1 + 36);
  f32x4 kb4[4];
  kb4[0] = *(const f32x4*)(kbp);
  kb4[1] = *(const f32x4*)(kbp + 4);
  kb4[2] = *(const f32x4*)(kbp + 32);
  kb4[3] = *(const f32x4*)(kbp + 36);

  // QK^T: K fragments shared by both q-tiles
  f32x4 st[2][4];
  #pragma unroll
  for (int t4 = 0; t4 < 4; ++t4) {
    const bf16x8 ka0 = *(const bf16x8*)(cbuf + ((t4 * 2 + 0) * 64 + lane) * 8);
    const bf16x8 ka1 = *(const bf16x8*)(cbuf + ((t4 * 2 + 1) * 64 + lane) * 8);
    #pragma unroll
    for (int tl = 0; tl < 2; ++tl) {
      f32x4 z = {0.f, 0.f, 0.f, 0.f};
      z = __builtin_amdgcn_mfma_f32_16x16x32_bf16(ka0, qh[tl][0], z, 0, 0, 0);
      z = __builtin_amdgcn_mfma_f32_16x16x32_bf16(ka1, qh[tl][1], z, 0, 0, 0);
      st[tl][t4] = z;
    }
  }

  // V fragments shared by both q-tiles
  const bf16x8 va00 = *(const bf16x8*)(cbuf + ((512 + 0 * 64) + lane) * 8);
  const bf16x8 va01 = *(const bf16x8*)(cbuf + ((512 + 1 * 64) + lane) * 8);
  const bf16x8 va10 = *(const bf16x8*)(cbuf + ((512 + 2 * 64) + lane) * 8);
  const bf16x8 va11 = *(const bf16x8*)(cbuf + ((512 + 3 * 64) + lane) * 8);

  #pragma unroll
  for (int tl = 0; tl < 2; ++tl) {
    float lg[16];
    #pragma unroll
    for (int t4 = 0; t4 < 4; ++t4) {
      #pragma unroll
      for (int r = 0; r < 4; ++r) lg[t4 * 4 + r] = st[tl][t4][r] + kb4[t4][r];
    }

    float cm = lg[0];
    #pragma unroll
    for (int j = 1; j < 16; ++j) cm = fmaxf(cm, lg[j]);
    cm = fmaxf(cm, __shfl_xor(cm, 16));
    cm = fmaxf(cm, __shfl_xor(cm, 32));
    const float mn = fmaxf(m[tl], cm);
    const float sc = __builtin_amdgcn_exp2f(m[tl] - mn);
    m[tl] = mn;

    unsigned eu[16];
    #pragma unroll
    for (int t4 = 0; t4 < 4; ++t4) {
      #pragma unroll
      for (int r = 0; r < 4; ++r)
        eu[t4 * 4 + r] = __float_as_uint(
            __builtin_amdgcn_exp2f(lg[t4 * 4 + r] - mn) * pi4[tl][t4][r]);
    }

    PF pf0, pf1;
    #pragma unroll
    for (int p = 0; p < 4; ++p) {
      pf0.i[p] = __builtin_amdgcn_perm(eu[2 * p + 1], eu[2 * p], 0x07060302u);
      pf1.i[p] = __builtin_amdgcn_perm(eu[8 + 2 * p + 1], eu[8 + 2 * p], 0x07060302u);
    }

    #pragma unroll
    for (int r = 0; r < 4; ++r) { o[tl][0][r] *= sc; o[tl][1][r] *= sc; ol[tl][r] *= sc; }

    o[tl][0] = __builtin_amdgcn_mfma_f32_16x16x32_bf16(va00, pf0.v, o[tl][0], 0, 0, 0);
    o[tl][0] = __builtin_amdgcn_mfma_f32_16x16x32_bf16(va01, pf1.v, o[tl][0], 0, 0, 0);
    o[tl][1] = __builtin_amdgcn_mfma_f32_16x16x32_bf16(va10, pf0.v, o[tl][1], 0, 0, 0);
    o[tl][1] = __builtin_amdgcn_mfma_f32_16x16x32_bf16(va11, pf1.v, o[tl][1], 0, 0, 0);
    // l accumulation on the matrix pipe: row-0 ones A-operand
    ol[tl] = __builtin_amdgcn_mfma_f32_16x16x32_bf16(ones, pf0.v, ol[tl], 0, 0, 0);
    ol[tl] = __builtin_amdgcn_mfma_f32_16x16x32_bf16(ones, pf1.v, ol[tl], 0, 0, 0);
  }
}

__global__ __launch_bounds__(256, 4) void attn_kernel(
    const short* __restrict__ Qh, const short* __restrict__ KV,
    const float* __restrict__ kb, const float* __restrict__ pi,
    float* __restrict__ part)
{
  __shared__ short skv[2][6144];   // 2 x 768 granules x 16 B
  // XCD swizzle: 8 q-blocks sharing (bh,sp) land on one XCD
  const int id = blockIdx.x;
  const int combo = id & 127;      // (bh<<2) | sp
  const int qblk  = id >> 7;       // 0..7
  const int bh = combo >> 2;
  const int sp = combo & 3;
  const int b = bh >> 3;
  const int wv = threadIdx.x >> 6;
  const int lane = threadIdx.x & 63;
  const int lo16 = lane & 15;
  const int quad = lane >> 4;
  const int qt0 = qblk * 8 + wv * 2;   // first of two q-tiles
  const int blk0 = sp * ITERS;

  bf16x8 qh[2][2];
  #pragma unroll
  for (int tl = 0; tl < 2; ++tl) {
    const size_t qoff = ((size_t)bh * LQ + (qt0 + tl) * 16 + lo16) * 64 + quad * 8;
    qh[tl][0] = *(const bf16x8*)(Qh + qoff);
    qh[tl][1] = *(const bf16x8*)(Qh + qoff + 32);
  }

  // direct pi: lane (lo16 -> q row, quad -> k octet) gather bases
  const float* pib0 = pi + ((size_t)(b * LQ + qt0 * 16 + lo16)) * LK
                      + sp * KPS + quad * 8;
  const float* pib1 = pib0 + (size_t)16 * LK;
  const float* kbbase = kb + (size_t)bh * LK + sp * KPS + quad * 8;

  bf16x8 ones;
  #pragma unroll
  for (int j = 0; j < 8; ++j) ones[j] = (lo16 == 0) ? (short)0x3F80 : (short)0;

  float m[2] = {-1e30f, -1e30f};
  f32x4 o[2][2] = {{{0.f,0.f,0.f,0.f},{0.f,0.f,0.f,0.f}},
                   {{0.f,0.f,0.f,0.f},{0.f,0.f,0.f,0.f}}};
  f32x4 ol[2] = {{0.f,0.f,0.f,0.f},{0.f,0.f,0.f,0.f}};

  // prologue: DMA buffer 0
  {
    const size_t gb = ((size_t)bh * 32 + blk0) * 768;
    #pragma unroll
    for (int c = 0; c < 3; ++c)
      gl_lds16(KV + (gb + c * 256 + wv * 64 + lane) * 8,
               &skv[0][c * 2048 + wv * 512]);
  }

  for (int it = 0; it < ITERS; it += 2) {
    __syncthreads();   // DMA for buffer0 (it) complete
    {
      const size_t gb = ((size_t)bh * 32 + blk0 + it + 1) * 768;
      #pragma unroll
      for (int c = 0; c < 3; ++c)
        gl_lds16(KV + (gb + c * 256 + wv * 64 + lane) * 8,
                 &skv[1][c * 2048 + wv * 512]);
    }
    attn_step2(skv[0], qh, pib0 + it * 64, pib1 + it * 64,
               kbbase + it * 64, ones, lane, m, o, ol);

    __syncthreads();   // DMA for buffer1 (it+1) complete
    if (it + 2 < ITERS) {
      const size_t gb = ((size_t)bh * 32 + blk0 + it + 2) * 768;
      #pragma unroll
      for (int c = 0; c < 3; ++c)
        gl_lds16(KV + (gb + c * 256 + wv * 64 + lane) * 8,
                 &skv[0][c * 2048 + wv * 512]);
    }
    attn_step2(skv[1], qh, pib0 + (it + 1) * 64, pib1 + (it + 1) * 64,
               kbbase + (it + 1) * 64, ones, lane, m, o, ol);
  }

  // partial out: [sp][bh][q] stride 36 floats: m, l, _, _, o[32]
  #pragma unroll
  for (int tl = 0; tl < 2; ++tl) {
    const int q = (qt0 + tl) * 16 + lo16;
    float* ppart = part + ((size_t)(sp * 32 + bh) * LQ + q) * 36;
    if (quad == 0) { ppart[0] = m[tl]; ppart[1] = ol[tl][0]; }
    *(f32x4*)(ppart + 4 + quad * 4)  = o[tl][0];
    *(f32x4*)(ppart + 20 + quad * 4) = o[tl][1];
  }
}

// ---------------------------------------------------------------------------
// Wo -> bf16 hi/lo split (row-major [n][k], same as Wo).
// ---------------------------------------------------------------------------
__global__ __launch_bounds__(256) void wo_prep_kernel(
    const float* __restrict__ Wo, short* __restrict__ WoH, short* __restrict__ WoL)
{
  const int i = (blockIdx.x * 256 + threadIdx.x) * 4;
  const f32x4 v = *(const f32x4*)(Wo + i);
  s16x4 h, l;
  #pragma unroll
  for (int j = 0; j < 4; ++j) {
    h[j] = f2bf(v[j]);
    l[j] = f2bf(v[j] - bf2f(h[j]));
  }
  *(s16x4*)(WoH + i) = h;
  *(s16x4*)(WoL + i) = l;
}

// ---------------------------------------------------------------------------
// Fused combine (4-way) + output GEMM via MFMA (hi/lo bf16 compensation).
// ---------------------------------------------------------------------------
__global__ __launch_bounds__(256) void out_kernel(
    const float* __restrict__ part, const short* __restrict__ WoH,
    const short* __restrict__ WoL, const float* __restrict__ bo,
    float* __restrict__ out)
{
  const int t = threadIdx.x;
  const int wv = t >> 6, lane = t & 63;
  const int lo16 = lane & 15, quad = lane >> 4;
  const int mt = blockIdx.x;                 // m-tile of 16 rows
  const size_t gq = (size_t)mt * 16 + lo16;  // ctx row for A fragment
  const int b = (int)(gq >> 10), qq = (int)(gq & (LQ - 1));

  // ---- A fragments (8 windows = 8 heads), combine SPLIT partials ----
  bf16x8 Ah[8], Al[8];
  #pragma unroll
  for (int win = 0; win < 8; ++win) {
    const size_t r = (size_t)(b * H_ + win) * LQ + qq;
    const float* p[SPLIT];
    float ms[SPLIT], ls[SPLIT];
    #pragma unroll
    for (int s = 0; s < SPLIT; ++s) {
      p[s] = part + (r + (size_t)s * (B_ * H_ * LQ)) * 36;
      ms[s] = p[s][0]; ls[s] = p[s][1];
    }
    float mM = ms[0];
    #pragma unroll
    for (int s = 1; s < SPLIT; ++s) mM = fmaxf(mM, ms[s]);
    float ws[SPLIT], den = 0.f;
    #pragma unroll
    for (int s = 0; s < SPLIT; ++s) {
      ws[s] = __builtin_amdgcn_exp2f(ms[s] - mM);
      den += ws[s] * ls[s];
    }
    const float inv = 1.f / den;

    float c8[8];
    #pragma unroll
    for (int j = 0; j < 8; ++j) c8[j] = 0.f;
    #pragma unroll
    for (int s = 0; s < SPLIT; ++s) {
      const f32x4 a0 = *(const f32x4*)(p[s] + 4 + quad * 8);
      const f32x4 a1 = *(const f32x4*)(p[s] + 8 + quad * 8);
      #pragma unroll
      for (int j = 0; j < 4; ++j) {
        c8[j]     += ws[s] * a0[j];
        c8[4 + j] += ws[s] * a1[j];
      }
    }
    #pragma unroll
    for (int j = 0; j < 8; ++j) {
      const float cv = c8[j] * inv;
      const short hi = f2bf(cv);
      Ah[win][j] = hi;
      Al[win][j] = f2bf(cv - bf2f(hi));
    }
  }

  // ---- 4 n-tiles of 16 cols each ----
  const int n0 = wv * 64;
  #pragma unroll
  for (int nt = 0; nt < 4; ++nt) {
    const int nb = n0 + nt * 16;
    const short* bh = WoH + (size_t)(nb + lo16) * HID_ + quad * 8;
    const short* bl = WoL + (size_t)(nb + lo16) * HID_ + quad * 8;
    const float bias = bo[nb + lo16];
    f32x4 acc = {bias, bias, bias, bias};
    #pragma unroll
    for (int win = 0; win < 8; ++win) {
      const bf16x8 Bh = *(const bf16x8*)(bh + win * 32);
      const bf16x8 Bl = *(const bf16x8*)(bl + win * 32);
      acc = __builtin_amdgcn_mfma_f32_16x16x32_bf16(Ah[win], Bh, acc, 0, 0, 0);
      acc = __builtin_amdgcn_mfma_f32_16x16x32_bf16(Al[win], Bh, acc, 0, 0, 0);
      acc = __builtin_amdgcn_mfma_f32_16x16x32_bf16(Ah[win], Bl, acc, 0, 0, 0);
    }
    #pragma unroll
    for (int r4 = 0; r4 < 4; ++r4)
      out[(size_t)(mt * 16 + quad * 4 + r4) * HID_ + nb + lo16] = acc[r4];
  }
}

// ---------------------------------------------------------------------------
extern "C" void kernel_launch(void* const* d_in, const int* in_sizes, int n_in,
                              void* d_out, int out_size, void* d_ws, size_t ws_size,
                              hipStream_t stream)
{
  const float* q_fp  = (const float*)d_in[0];
  const float* v_ret = (const float*)d_in[1];
  const float* pi    = (const float*)d_in[2];
  const float* Wq_s  = (const float*)d_in[3];
  const float* bq_s  = (const float*)d_in[4];
  const float* Wk_s  = (const float*)d_in[5];
  const float* bk_s  = (const float*)d_in[6];
  const float* Wq_w  = (const float*)d_in[7];
  const float* bq_w  = (const float*)d_in[8];
  const float* Wk_w  = (const float*)d_in[9];
  const float* bk_w  = (const float*)d_in[10];
  const float* Wv    = (const float*)d_in[11];
  const float* bv    = (const float*)d_in[12];
  const float* Wo    = (const float*)d_in[13];
  const float* bo    = (const float*)d_in[14];
  const float* wb    = (const float*)d_in[15];
  float* out = (float*)d_out;

  // ws: Qh 4MB | KV 12MB | kb 256KB | part 18.9MB | WoH/WoL 256KB (~35.5 MB)
  short* Qh   = (short*)d_ws;                     // 2,097,152 sh
  short* KV   = Qh + (size_t)2097152;             // 6,291,456 sh
  float* kbuf = (float*)(KV + (size_t)6291456);   //    65,536 fl
  float* part = kbuf + (size_t)65536;             // 4,718,592 fl
  short* WoH  = (short*)(part + (size_t)4718592); //    65,536 sh
  short* WoL  = WoH + (size_t)65536;              //    65,536 sh

  proj_q_kernel<<<dim3(LQ / 64, 32), 256, 0, stream>>>(
      q_fp, Wq_s, bq_s, Wq_w, bq_w, wb, Qh);
  projk_pack_kernel<<<dim3(LK / 64, 32), 256, 0, stream>>>(
      v_ret, Wk_s, bk_s, Wk_w, bk_w, Wv, bv, wb, KV, kbuf);
  attn_kernel<<<(LQ / 128) * 32 * SPLIT, 256, 0, stream>>>(Qh, KV, kbuf, pi, part);
  wo_prep_kernel<<<64, 256, 0, stream>>>(Wo, WoH, WoL);
  out_kernel<<<(B_ * LQ) / 16, 256, 0, stream>>>(part, WoH, WoL, bo, out);
}

// Round 10
// 177.215 us; speedup vs baseline: 1.0338x; 1.0338x over previous
//
#include <hip/hip_runtime.h>
#include <hip/hip_bf16.h>
#include <cstdint>

#define B_    4
#define LQ    1024
#define LK    2048
#define FEAT  11
#define SP_   8
#define WD_   3
#define H_    8
#define HID_  256
#define LOG2E 1.4426950408889634f
#define SPLIT 4
#define KPS   (LK / SPLIT)    // 512 k per split
#define ITERS (KPS / 64)      // 8 rounds of 64 k

typedef __attribute__((ext_vector_type(4))) float f32x4;
typedef __attribute__((ext_vector_type(8))) short bf16x8;
typedef __attribute__((ext_vector_type(4))) short s16x4;

__device__ __forceinline__ float sigmoidf_(float x) { return 1.f / (1.f + __expf(-x)); }

__device__ __forceinline__ short f2bf(float f) {
  unsigned u = __float_as_uint(f);
  u += 0x7fffu + ((u >> 16) & 1u);
  return (short)(u >> 16);
}
__device__ __forceinline__ float bf2f(short s) {
  return __uint_as_float(((unsigned)(unsigned short)s) << 16);
}

__device__ __forceinline__ void gl_lds16(const void* g, void* l) {
  __builtin_amdgcn_global_load_lds(
      (const __attribute__((address_space(1))) unsigned int*)g,
      (__attribute__((address_space(3))) unsigned int*)l, 16, 0, 0);
}

// ---------------------------------------------------------------------------
// Q projection -> Qh bf16 [bh][q][64]; scales (c1,c2) and log2e folded in.
// Block = (64-q tile, bh); thread (q_local, part) computes 8+8 features.
// ---------------------------------------------------------------------------
__global__ __launch_bounds__(256) void proj_q_kernel(
    const float* __restrict__ q_fp, const float* __restrict__ Wq_s,
    const float* __restrict__ bq_s, const float* __restrict__ Wq_w,
    const float* __restrict__ bq_w, const float* __restrict__ wb,
    short* __restrict__ Qh)
{
  const int blk = blockIdx.x, bh = blockIdx.y;
  const int b = bh >> 3, h = bh & 7;
  const int t = threadIdx.x;
  const int ql = t >> 2, part = t & 3;
  const int q = blk * 64 + ql;
  const float alpha = sigmoidf_(wb[0]);
  const float c1 = (1.f - alpha) * 0.17677669529663687f * LOG2E;
  const float c2 = 2.f * alpha * 10.f * LOG2E;

  const float* x = q_fp + (size_t)(b * LQ + q) * FEAT;
  float xs[FEAT];
  #pragma unroll
  for (int f = 0; f < FEAT; ++f) xs[f] = x[f];

  const size_t base = ((size_t)bh * LQ + q) * 64 + part * 8;
  s16x4 out_s[2], out_w[2];
  #pragma unroll
  for (int i = 0; i < 8; ++i) {
    const int dg = h * 32 + part * 8 + i;
    float s = bq_s[dg];
    #pragma unroll
    for (int f = 0; f < SP_; ++f) s += xs[f] * Wq_s[dg * SP_ + f];
    float w = bq_w[dg];
    #pragma unroll
    for (int f = 0; f < WD_; ++f) w += xs[SP_ + f] * Wq_w[dg * WD_ + f];
    out_s[i >> 2][i & 3] = f2bf(c1 * s);
    out_w[i >> 2][i & 3] = f2bf(c2 * w);
  }
  *(s16x4*)(Qh + base)      = out_s[0];
  *(s16x4*)(Qh + base + 4)  = out_s[1];
  *(s16x4*)(Qh + base + 32) = out_w[0];
  *(s16x4*)(Qh + base + 36) = out_w[1];
}

// ---------------------------------------------------------------------------
// Fused K/V projection + fragment prepack. Block = (64-k tile, bh).
// ---------------------------------------------------------------------------
__global__ __launch_bounds__(256) void projk_pack_kernel(
    const float* __restrict__ v_ret, const float* __restrict__ Wk_s,
    const float* __restrict__ bk_s, const float* __restrict__ Wk_w,
    const float* __restrict__ bk_w, const float* __restrict__ Wv,
    const float* __restrict__ bv,   const float* __restrict__ wb,
    short* __restrict__ KV, float* __restrict__ kb)
{
  __shared__ float ldsv[64][33];
  const int blk = blockIdx.x, bh = blockIdx.y;
  const int b = bh >> 3, h = bh & 7;
  const int t = threadIdx.x;
  const int kl = t >> 2, part = t & 3;
  const int k = blk * 64 + kl;
  const float alpha = sigmoidf_(wb[0]);

  const float* x = v_ret + (size_t)(b * LK + k) * FEAT;
  float xs[FEAT];
  #pragma unroll
  for (int f = 0; f < FEAT; ++f) xs[f] = x[f];

  float s8[8], w8[8];
  #pragma unroll
  for (int i = 0; i < 8; ++i) {
    const int d = h * 32 + part * 8 + i;
    float s = bk_s[d];
    #pragma unroll
    for (int f = 0; f < SP_; ++f) s += xs[f] * Wk_s[d * SP_ + f];
    float w = bk_w[d];
    #pragma unroll
    for (int f = 0; f < WD_; ++f) w += xs[SP_ + f] * Wk_w[d * WD_ + f];
    float v = bv[d];
    #pragma unroll
    for (int f = 0; f < FEAT; ++f) v += xs[f] * Wv[d * FEAT + f];
    s8[i] = s; w8[i] = w;
    ldsv[kl][part * 8 + i] = v;
  }

  float sq = 0.f;
  #pragma unroll
  for (int i = 0; i < 8; ++i) sq += w8[i] * w8[i];
  sq += __shfl_xor(sq, 1);
  sq += __shfl_xor(sq, 2);
  if (part == 0) kb[(size_t)bh * LK + k] = -10.f * alpha * LOG2E * sq;

  const int a  = kl >> 5;
  const int bb = (kl >> 2) & 1;
  const int p  = kl - a * 32 - bb * 4;
  const int lo = ((p >> 3) << 2) | (p & 3);
  const int t4 = a * 2 + bb;
  const size_t base = ((size_t)bh * 32 + blk) * 768;

  bf16x8 hs, hw;
  #pragma unroll
  for (int i = 0; i < 8; ++i) { hs[i] = f2bf(s8[i]); hw[i] = f2bf(w8[i]); }
  *(bf16x8*)(KV + (base + (t4 * 2 + 0) * 64 + part * 16 + lo) * 8) = hs;
  *(bf16x8*)(KV + (base + (t4 * 2 + 1) * 64 + part * 16 + lo) * 8) = hw;

  __syncthreads();

  {
    const int j = t >> 6, l = t & 63;
    const int dt = j >> 1, kw = j & 1;
    const int lo2 = l & 15, quad = l >> 4;
    const int d = dt * 16 + lo2;
    bf16x8 hv;
    #pragma unroll
    for (int i = 0; i < 8; ++i)
      hv[i] = f2bf(ldsv[kw * 32 + quad * 8 + i][d]);
    *(bf16x8*)(KV + (base + 512 + t) * 8) = hv;
  }
}

// ---------------------------------------------------------------------------
// pi prepack -> bf16, fragment-lane order.
// Tile (b, qt, kblk): 128 granules of 8 bf16. Granule g = pair*64 + lane
// (lane = quad*16+lo): holds pi[b][qt*16+lo][kblk*64 + pair*32 + quad*8 + j].
// ---------------------------------------------------------------------------
__global__ __launch_bounds__(256) void pi_prepack_kernel(
    const float* __restrict__ pi, short* __restrict__ piB)
{
  const int Gid = blockIdx.x * 256 + threadIdx.x;   // granule id
  const int g    = Gid & 127;
  const int kblk = (Gid >> 7) & 31;
  const int qt   = (Gid >> 12) & 63;
  const int b    = Gid >> 18;
  const int pair = g >> 6;
  const int quad = (g >> 4) & 3, lo = g & 15;
  const int q = qt * 16 + lo;
  const int k = kblk * 64 + pair * 32 + quad * 8;
  const float* src = pi + ((size_t)(b * LQ + q) * LK + k);
  const f32x4 v0 = *(const f32x4*)(src);
  const f32x4 v1 = *(const f32x4*)(src + 4);
  bf16x8 hv;
  #pragma unroll
  for (int j = 0; j < 4; ++j) { hv[j] = f2bf(v0[j]); hv[4 + j] = f2bf(v1[j]); }
  *(bf16x8*)(piB + (size_t)Gid * 8) = hv;
}

// ---------------------------------------------------------------------------
// Flash attention: 32 q per wave (2 q-tiles share K/V LDS fragments),
// LDS double buffer via global_load_lds, log-free softmax, l via MFMA
// ones-row, SPLIT=4, XCD-swizzled 1-D grid, bf16 fragment-ordered pi.
// ---------------------------------------------------------------------------
union PF { int i[4]; bf16x8 v; };

__device__ __forceinline__ void attn_step2(
    const short* __restrict__ cbuf, const bf16x8 qh[2][2],
    const short* __restrict__ pit0, const short* __restrict__ pit1,
    const float* __restrict__ kbp, const bf16x8 ones, int lane,
    float m[2], f32x4 o[2][2], f32x4 ol[2])
{
  // pi (bf16, coalesced fragment order) + kb (quad-broadcast), issued first
  bf16x8 pg[2][2];
  pg[0][0] = *(const bf16x8*)(pit0);
  pg[0][1] = *(const bf16x8*)(pit0 + 512);
  pg[1][0] = *(const bf16x8*)(pit1);
  pg[1][1] = *(const bf16x8*)(pit1 + 512);
  f32x4 kb4[4];
  kb4[0] = *(const f32x4*)(kbp);
  kb4[1] = *(const f32x4*)(kbp + 4);
  kb4[2] = *(const f32x4*)(kbp + 32);
  kb4[3] = *(const f32x4*)(kbp + 36);

  // QK^T: K fragments shared by both q-tiles
  f32x4 st[2][4];
  #pragma unroll
  for (int t4 = 0; t4 < 4; ++t4) {
    const bf16x8 ka0 = *(const bf16x8*)(cbuf + ((t4 * 2 + 0) * 64 + lane) * 8);
    const bf16x8 ka1 = *(const bf16x8*)(cbuf + ((t4 * 2 + 1) * 64 + lane) * 8);
    #pragma unroll
    for (int tl = 0; tl < 2; ++tl) {
      f32x4 z = {0.f, 0.f, 0.f, 0.f};
      z = __builtin_amdgcn_mfma_f32_16x16x32_bf16(ka0, qh[tl][0], z, 0, 0, 0);
      z = __builtin_amdgcn_mfma_f32_16x16x32_bf16(ka1, qh[tl][1], z, 0, 0, 0);
      st[tl][t4] = z;
    }
  }

  // V fragments shared by both q-tiles
  const bf16x8 va00 = *(const bf16x8*)(cbuf + ((512 + 0 * 64) + lane) * 8);
  const bf16x8 va01 = *(const bf16x8*)(cbuf + ((512 + 1 * 64) + lane) * 8);
  const bf16x8 va10 = *(const bf16x8*)(cbuf + ((512 + 2 * 64) + lane) * 8);
  const bf16x8 va11 = *(const bf16x8*)(cbuf + ((512 + 3 * 64) + lane) * 8);

  #pragma unroll
  for (int tl = 0; tl < 2; ++tl) {
    float lg[16];
    #pragma unroll
    for (int t4 = 0; t4 < 4; ++t4) {
      #pragma unroll
      for (int r = 0; r < 4; ++r) lg[t4 * 4 + r] = st[tl][t4][r] + kb4[t4][r];
    }

    float cm = lg[0];
    #pragma unroll
    for (int j = 1; j < 16; ++j) cm = fmaxf(cm, lg[j]);
    cm = fmaxf(cm, __shfl_xor(cm, 16));
    cm = fmaxf(cm, __shfl_xor(cm, 32));
    const float mn = fmaxf(m[tl], cm);
    const float sc = __builtin_amdgcn_exp2f(m[tl] - mn);
    m[tl] = mn;

    unsigned eu[16];
    #pragma unroll
    for (int j = 0; j < 16; ++j) {
      const float pif = bf2f(pg[tl][j >> 3][j & 7]);
      eu[j] = __float_as_uint(__builtin_amdgcn_exp2f(lg[j] - mn) * pif);
    }

    PF pf0, pf1;
    #pragma unroll
    for (int p = 0; p < 4; ++p) {
      pf0.i[p] = __builtin_amdgcn_perm(eu[2 * p + 1], eu[2 * p], 0x07060302u);
      pf1.i[p] = __builtin_amdgcn_perm(eu[8 + 2 * p + 1], eu[8 + 2 * p], 0x07060302u);
    }

    #pragma unroll
    for (int r = 0; r < 4; ++r) { o[tl][0][r] *= sc; o[tl][1][r] *= sc; ol[tl][r] *= sc; }

    o[tl][0] = __builtin_amdgcn_mfma_f32_16x16x32_bf16(va00, pf0.v, o[tl][0], 0, 0, 0);
    o[tl][0] = __builtin_amdgcn_mfma_f32_16x16x32_bf16(va01, pf1.v, o[tl][0], 0, 0, 0);
    o[tl][1] = __builtin_amdgcn_mfma_f32_16x16x32_bf16(va10, pf0.v, o[tl][1], 0, 0, 0);
    o[tl][1] = __builtin_amdgcn_mfma_f32_16x16x32_bf16(va11, pf1.v, o[tl][1], 0, 0, 0);
    // l accumulation on the matrix pipe: row-0 ones A-operand
    ol[tl] = __builtin_amdgcn_mfma_f32_16x16x32_bf16(ones, pf0.v, ol[tl], 0, 0, 0);
    ol[tl] = __builtin_amdgcn_mfma_f32_16x16x32_bf16(ones, pf1.v, ol[tl], 0, 0, 0);
  }
}

__global__ __launch_bounds__(256, 4) void attn_kernel(
    const short* __restrict__ Qh, const short* __restrict__ KV,
    const float* __restrict__ kb, const short* __restrict__ piB,
    float* __restrict__ part)
{
  __shared__ short skv[2][6144];   // 2 x 768 granules x 16 B
  // XCD swizzle: 8 q-blocks sharing (bh,sp) land on one XCD
  const int id = blockIdx.x;
  const int combo = id & 127;      // (bh<<2) | sp
  const int qblk  = id >> 7;       // 0..7
  const int bh = combo >> 2;
  const int sp = combo & 3;
  const int b = bh >> 3;
  const int wv = threadIdx.x >> 6;
  const int lane = threadIdx.x & 63;
  const int lo16 = lane & 15;
  const int quad = lane >> 4;
  const int qt0 = qblk * 8 + wv * 2;   // first of two q-tiles
  const int blk0 = sp * ITERS;

  bf16x8 qh[2][2];
  #pragma unroll
  for (int tl = 0; tl < 2; ++tl) {
    const size_t qoff = ((size_t)bh * LQ + (qt0 + tl) * 16 + lo16) * 64 + quad * 8;
    qh[tl][0] = *(const bf16x8*)(Qh + qoff);
    qh[tl][1] = *(const bf16x8*)(Qh + qoff + 32);
  }

  const short* pit0 = piB + ((((size_t)(b * 64 + qt0) * 32) + blk0) * 128 + lane) * 8;
  const short* pit1 = piB + ((((size_t)(b * 64 + qt0 + 1) * 32) + blk0) * 128 + lane) * 8;
  const float* kbbase = kb + (size_t)bh * LK + sp * KPS + quad * 8;

  bf16x8 ones;
  #pragma unroll
  for (int j = 0; j < 8; ++j) ones[j] = (lo16 == 0) ? (short)0x3F80 : (short)0;

  float m[2] = {-1e30f, -1e30f};
  f32x4 o[2][2] = {{{0.f,0.f,0.f,0.f},{0.f,0.f,0.f,0.f}},
                   {{0.f,0.f,0.f,0.f},{0.f,0.f,0.f,0.f}}};
  f32x4 ol[2] = {{0.f,0.f,0.f,0.f},{0.f,0.f,0.f,0.f}};

  // prologue: DMA buffer 0
  {
    const size_t gb = ((size_t)bh * 32 + blk0) * 768;
    #pragma unroll
    for (int c = 0; c < 3; ++c)
      gl_lds16(KV + (gb + c * 256 + wv * 64 + lane) * 8,
               &skv[0][c * 2048 + wv * 512]);
  }

  for (int it = 0; it < ITERS; it += 2) {
    __syncthreads();   // DMA for buffer0 (it) complete
    {
      const size_t gb = ((size_t)bh * 32 + blk0 + it + 1) * 768;
      #pragma unroll
      for (int c = 0; c < 3; ++c)
        gl_lds16(KV + (gb + c * 256 + wv * 64 + lane) * 8,
                 &skv[1][c * 2048 + wv * 512]);
    }
    attn_step2(skv[0], qh, pit0 + it * 1024, pit1 + it * 1024,
               kbbase + it * 64, ones, lane, m, o, ol);

    __syncthreads();   // DMA for buffer1 (it+1) complete
    if (it + 2 < ITERS) {
      const size_t gb = ((size_t)bh * 32 + blk0 + it + 2) * 768;
      #pragma unroll
      for (int c = 0; c < 3; ++c)
        gl_lds16(KV + (gb + c * 256 + wv * 64 + lane) * 8,
                 &skv[0][c * 2048 + wv * 512]);
    }
    attn_step2(skv[1], qh, pit0 + (it + 1) * 1024, pit1 + (it + 1) * 1024,
               kbbase + (it + 1) * 64, ones, lane, m, o, ol);
  }

  // partial out: [sp][bh][q] stride 36 floats: m, l, _, _, o[32]
  #pragma unroll
  for (int tl = 0; tl < 2; ++tl) {
    const int q = (qt0 + tl) * 16 + lo16;
    float* ppart = part + ((size_t)(sp * 32 + bh) * LQ + q) * 36;
    if (quad == 0) { ppart[0] = m[tl]; ppart[1] = ol[tl][0]; }
    *(f32x4*)(ppart + 4 + quad * 4)  = o[tl][0];
    *(f32x4*)(ppart + 20 + quad * 4) = o[tl][1];
  }
}

// ---------------------------------------------------------------------------
// Wo -> bf16 hi/lo split (row-major [n][k], same as Wo).
// ---------------------------------------------------------------------------
__global__ __launch_bounds__(256) void wo_prep_kernel(
    const float* __restrict__ Wo, short* __restrict__ WoH, short* __restrict__ WoL)
{
  const int i = (blockIdx.x * 256 + threadIdx.x) * 4;
  const f32x4 v = *(const f32x4*)(Wo + i);
  s16x4 h, l;
  #pragma unroll
  for (int j = 0; j < 4; ++j) {
    h[j] = f2bf(v[j]);
    l[j] = f2bf(v[j] - bf2f(h[j]));
  }
  *(s16x4*)(WoH + i) = h;
  *(s16x4*)(WoL + i) = l;
}

// ---------------------------------------------------------------------------
// Fused combine (4-way) + output GEMM via MFMA (hi/lo bf16 compensation).
// Stage 1: cooperative A-build — thread (win,row,quadpair) merges SPLIT
// partials for 2 quads, packs Ah/Al granules into LDS.
// Stage 2: 4 waves x 4 n-tiles of 16 cols; A from LDS (ds_read_b128).
// ---------------------------------------------------------------------------
__global__ __launch_bounds__(256) void out_kernel(
    const float* __restrict__ part, const short* __restrict__ WoH,
    const short* __restrict__ WoL, const float* __restrict__ bo,
    float* __restrict__ out)
{
  __shared__ short lA[2][8 * 64 * 8];   // [hi/lo][(win*64+lane)*8]
  const int t = threadIdx.x;
  const int mt = blockIdx.x;            // m-tile of 16 rows

  // ---- stage 1: cooperative A-build ----
  {
    const int win = t >> 5;             // 0..7
    const int row = (t >> 1) & 15;      // 0..15
    const int qp  = t & 1;              // quads {0,1} or {2,3}
    const size_t gq = (size_t)mt * 16 + row;
    const int b = (int)(gq >> 10), qq = (int)(gq & (LQ - 1));
    const size_t r = (size_t)(b * H_ + win) * LQ + qq;

    const float* p[SPLIT];
    float ms[SPLIT], ls[SPLIT];
    #pragma unroll
    for (int s = 0; s < SPLIT; ++s) {
      p[s] = part + (r + (size_t)s * (B_ * H_ * LQ)) * 36;
      ms[s] = p[s][0]; ls[s] = p[s][1];
    }
    float mM = ms[0];
    #pragma unroll
    for (int s = 1; s < SPLIT; ++s) mM = fmaxf(mM, ms[s]);
    float ws[SPLIT], den = 0.f;
    #pragma unroll
    for (int s = 0; s < SPLIT; ++s) {
      ws[s] = __builtin_amdgcn_exp2f(ms[s] - mM);
      den += ws[s] * ls[s];
    }
    const float inv = 1.f / den;

    #pragma unroll
    for (int q2 = 0; q2 < 2; ++q2) {
      const int quad = qp * 2 + q2;
      float c8[8];
      #pragma unroll
      for (int j = 0; j < 8; ++j) c8[j] = 0.f;
      #pragma unroll
      for (int s = 0; s < SPLIT; ++s) {
        const f32x4 a0 = *(const f32x4*)(p[s] + 4 + quad * 8);
        const f32x4 a1 = *(const f32x4*)(p[s] + 8 + quad * 8);
        #pragma unroll
        for (int j = 0; j < 4; ++j) {
          c8[j]     += ws[s] * a0[j];
          c8[4 + j] += ws[s] * a1[j];
        }
      }
      bf16x8 ah, al;
      #pragma unroll
      for (int j = 0; j < 8; ++j) {
        const float cv = c8[j] * inv;
        const short hi = f2bf(cv);
        ah[j] = hi;
        al[j] = f2bf(cv - bf2f(hi));
      }
      const int gidx = (win * 64 + quad * 16 + row) * 8;
      *(bf16x8*)(&lA[0][gidx]) = ah;
      *(bf16x8*)(&lA[1][gidx]) = al;
    }
  }
  __syncthreads();

  // ---- stage 2: GEMM ----
  const int wv = t >> 6, lane = t & 63;
  const int lo16 = lane & 15, quad = lane >> 4;

  bf16x8 Ah[8], Al[8];
  #pragma unroll
  for (int win = 0; win < 8; ++win) {
    Ah[win] = *(const bf16x8*)(&lA[0][(win * 64 + lane) * 8]);
    Al[win] = *(const bf16x8*)(&lA[1][(win * 64 + lane) * 8]);
  }

  const int n0 = wv * 64;
  #pragma unroll
  for (int nt = 0; nt < 4; ++nt) {
    const int nb = n0 + nt * 16;
    const short* bh = WoH + (size_t)(nb + lo16) * HID_ + quad * 8;
    const short* bl = WoL + (size_t)(nb + lo16) * HID_ + quad * 8;
    const float bias = bo[nb + lo16];
    f32x4 acc = {bias, bias, bias, bias};
    #pragma unroll
    for (int win = 0; win < 8; ++win) {
      const bf16x8 Bh = *(const bf16x8*)(bh + win * 32);
      const bf16x8 Bl = *(const bf16x8*)(bl + win * 32);
      acc = __builtin_amdgcn_mfma_f32_16x16x32_bf16(Ah[win], Bh, acc, 0, 0, 0);
      acc = __builtin_amdgcn_mfma_f32_16x16x32_bf16(Al[win], Bh, acc, 0, 0, 0);
      acc = __builtin_amdgcn_mfma_f32_16x16x32_bf16(Ah[win], Bl, acc, 0, 0, 0);
    }
    #pragma unroll
    for (int r4 = 0; r4 < 4; ++r4)
      out[(size_t)(mt * 16 + quad * 4 + r4) * HID_ + nb + lo16] = acc[r4];
  }
}

// ---------------------------------------------------------------------------
extern "C" void kernel_launch(void* const* d_in, const int* in_sizes, int n_in,
                              void* d_out, int out_size, void* d_ws, size_t ws_size,
                              hipStream_t stream)
{
  const float* q_fp  = (const float*)d_in[0];
  const float* v_ret = (const float*)d_in[1];
  const float* pi    = (const float*)d_in[2];
  const float* Wq_s  = (const float*)d_in[3];
  const float* bq_s  = (const float*)d_in[4];
  const float* Wk_s  = (const float*)d_in[5];
  const float* bk_s  = (const float*)d_in[6];
  const float* Wq_w  = (const float*)d_in[7];
  const float* bq_w  = (const float*)d_in[8];
  const float* Wk_w  = (const float*)d_in[9];
  const float* bk_w  = (const float*)d_in[10];
  const float* Wv    = (const float*)d_in[11];
  const float* bv    = (const float*)d_in[12];
  const float* Wo    = (const float*)d_in[13];
  const float* bo    = (const float*)d_in[14];
  const float* wb    = (const float*)d_in[15];
  float* out = (float*)d_out;

  // ws: Qh 4MB | KV 12MB | kb 256KB | piB 16.8MB | part 18.9MB | WoH/L 256KB
  short* Qh   = (short*)d_ws;                     // 2,097,152 sh
  short* KV   = Qh + (size_t)2097152;             // 6,291,456 sh
  float* kbuf = (float*)(KV + (size_t)6291456);   //    65,536 fl
  short* piB  = (short*)(kbuf + (size_t)65536);   // 8,388,608 sh
  float* part = (float*)(piB + (size_t)8388608);  // 4,718,592 fl
  short* WoH  = (short*)(part + (size_t)4718592); //    65,536 sh
  short* WoL  = WoH + (size_t)65536;              //    65,536 sh

  proj_q_kernel<<<dim3(LQ / 64, 32), 256, 0, stream>>>(
      q_fp, Wq_s, bq_s, Wq_w, bq_w, wb, Qh);
  projk_pack_kernel<<<dim3(LK / 64, 32), 256, 0, stream>>>(
      v_ret, Wk_s, bk_s, Wk_w, bk_w, Wv, bv, wb, KV, kbuf);
  pi_prepack_kernel<<<4096, 256, 0, stream>>>(pi, piB);
  attn_kernel<<<(LQ / 128) * 32 * SPLIT, 256, 0, stream>>>(Qh, KV, kbuf, piB, part);
  wo_prep_kernel<<<64, 256, 0, stream>>>(Wo, WoH, WoL);
  out_kernel<<<(B_ * LQ) / 16, 256, 0, stream>>>(part, WoH, WoL, bo, out);
}

// Round 11
// 173.362 us; speedup vs baseline: 1.0567x; 1.0222x over previous
//
#include <hip/hip_runtime.h>
#include <hip/hip_bf16.h>
#include <cstdint>

#define B_    4
#define LQ    1024
#define LK    2048
#define FEAT  11
#define SP_   8
#define WD_   3
#define H_    8
#define HID_  256
#define LOG2E 1.4426950408889634f
#define SPLIT 4
#define KPS   (LK / SPLIT)    // 512 k per split
#define ITERS (KPS / 64)      // 8 rounds of 64 k

typedef __attribute__((ext_vector_type(4))) float f32x4;
typedef __attribute__((ext_vector_type(8))) short bf16x8;
typedef __attribute__((ext_vector_type(4))) short s16x4;

__device__ __forceinline__ float sigmoidf_(float x) { return 1.f / (1.f + __expf(-x)); }

__device__ __forceinline__ short f2bf(float f) {
  unsigned u = __float_as_uint(f);
  u += 0x7fffu + ((u >> 16) & 1u);
  return (short)(u >> 16);
}
__device__ __forceinline__ float bf2f(short s) {
  return __uint_as_float(((unsigned)(unsigned short)s) << 16);
}

__device__ __forceinline__ void gl_lds16(const void* g, void* l) {
  __builtin_amdgcn_global_load_lds(
      (const __attribute__((address_space(1))) unsigned int*)g,
      (__attribute__((address_space(3))) unsigned int*)l, 16, 0, 0);
}

// ---------------------------------------------------------------------------
// Fused prep: one dispatch covering four independent sub-kernels, selected
// by blockIdx.x range (pi-prepack blocks first: heaviest HBM stream).
//   [0, 4096)        pi  -> piB   (bf16, fragment-lane order)
//   [4096, 4608)     q   -> Qh    (projection, scales folded)
//   [4608, 5632)     kv  -> KV,kb (projection + fragment prepack)
//   [5632, 5696)     Wo  -> WoH/WoL (hi/lo bf16 split)
// ---------------------------------------------------------------------------
#define PREP_PI0   0
#define PREP_Q0    4096
#define PREP_K0    4608
#define PREP_W0    5632
#define PREP_NBLK  5696

__global__ __launch_bounds__(256) void prep_kernel(
    const float* __restrict__ q_fp, const float* __restrict__ v_ret,
    const float* __restrict__ pi,
    const float* __restrict__ Wq_s, const float* __restrict__ bq_s,
    const float* __restrict__ Wq_w, const float* __restrict__ bq_w,
    const float* __restrict__ Wk_s, const float* __restrict__ bk_s,
    const float* __restrict__ Wk_w, const float* __restrict__ bk_w,
    const float* __restrict__ Wv,   const float* __restrict__ bv,
    const float* __restrict__ Wo,   const float* __restrict__ wb,
    short* __restrict__ Qh, short* __restrict__ KV, float* __restrict__ kb,
    short* __restrict__ piB, short* __restrict__ WoH, short* __restrict__ WoL)
{
  const int bid = blockIdx.x;
  const int t = threadIdx.x;

  if (bid < PREP_Q0) {
    // ---------------- pi prepack -> bf16 fragment-lane order ----------------
    const int Gid = bid * 256 + t;      // granule id
    const int g    = Gid & 127;
    const int kblk = (Gid >> 7) & 31;
    const int qt   = (Gid >> 12) & 63;
    const int b    = Gid >> 18;
    const int pair = g >> 6;
    const int quad = (g >> 4) & 3, lo = g & 15;
    const int q = qt * 16 + lo;
    const int k = kblk * 64 + pair * 32 + quad * 8;
    const float* src = pi + ((size_t)(b * LQ + q) * LK + k);
    const f32x4 v0 = *(const f32x4*)(src);
    const f32x4 v1 = *(const f32x4*)(src + 4);
    bf16x8 hv;
    #pragma unroll
    for (int j = 0; j < 4; ++j) { hv[j] = f2bf(v0[j]); hv[4 + j] = f2bf(v1[j]); }
    *(bf16x8*)(piB + (size_t)Gid * 8) = hv;

  } else if (bid < PREP_K0) {
    // ---------------- Q projection ----------------
    const int idx = bid - PREP_Q0;      // 0..511
    const int blk = idx & 15, bh = idx >> 4;
    const int b = bh >> 3, h = bh & 7;
    const int ql = t >> 2, part = t & 3;
    const int q = blk * 64 + ql;
    const float alpha = sigmoidf_(wb[0]);
    const float c1 = (1.f - alpha) * 0.17677669529663687f * LOG2E;
    const float c2 = 2.f * alpha * 10.f * LOG2E;

    const float* x = q_fp + (size_t)(b * LQ + q) * FEAT;
    float xs[FEAT];
    #pragma unroll
    for (int f = 0; f < FEAT; ++f) xs[f] = x[f];

    const size_t base = ((size_t)bh * LQ + q) * 64 + part * 8;
    s16x4 out_s[2], out_w[2];
    #pragma unroll
    for (int i = 0; i < 8; ++i) {
      const int dg = h * 32 + part * 8 + i;
      float s = bq_s[dg];
      #pragma unroll
      for (int f = 0; f < SP_; ++f) s += xs[f] * Wq_s[dg * SP_ + f];
      float w = bq_w[dg];
      #pragma unroll
      for (int f = 0; f < WD_; ++f) w += xs[SP_ + f] * Wq_w[dg * WD_ + f];
      out_s[i >> 2][i & 3] = f2bf(c1 * s);
      out_w[i >> 2][i & 3] = f2bf(c2 * w);
    }
    *(s16x4*)(Qh + base)      = out_s[0];
    *(s16x4*)(Qh + base + 4)  = out_s[1];
    *(s16x4*)(Qh + base + 32) = out_w[0];
    *(s16x4*)(Qh + base + 36) = out_w[1];

  } else if (bid < PREP_W0) {
    // ---------------- K/V projection + fragment prepack ----------------
    __shared__ float ldsv[64][33];
    const int idx = bid - PREP_K0;      // 0..1023
    const int blk = idx & 31, bh = idx >> 5;
    const int b = bh >> 3, h = bh & 7;
    const int kl = t >> 2, part = t & 3;
    const int k = blk * 64 + kl;
    const float alpha = sigmoidf_(wb[0]);

    const float* x = v_ret + (size_t)(b * LK + k) * FEAT;
    float xs[FEAT];
    #pragma unroll
    for (int f = 0; f < FEAT; ++f) xs[f] = x[f];

    float s8[8], w8[8];
    #pragma unroll
    for (int i = 0; i < 8; ++i) {
      const int d = h * 32 + part * 8 + i;
      float s = bk_s[d];
      #pragma unroll
      for (int f = 0; f < SP_; ++f) s += xs[f] * Wk_s[d * SP_ + f];
      float w = bk_w[d];
      #pragma unroll
      for (int f = 0; f < WD_; ++f) w += xs[SP_ + f] * Wk_w[d * WD_ + f];
      float v = bv[d];
      #pragma unroll
      for (int f = 0; f < FEAT; ++f) v += xs[f] * Wv[d * FEAT + f];
      s8[i] = s; w8[i] = w;
      ldsv[kl][part * 8 + i] = v;
    }

    float sq = 0.f;
    #pragma unroll
    for (int i = 0; i < 8; ++i) sq += w8[i] * w8[i];
    sq += __shfl_xor(sq, 1);
    sq += __shfl_xor(sq, 2);
    if (part == 0) kb[(size_t)bh * LK + k] = -10.f * alpha * LOG2E * sq;

    const int a  = kl >> 5;
    const int bb = (kl >> 2) & 1;
    const int p  = kl - a * 32 - bb * 4;
    const int lo = ((p >> 3) << 2) | (p & 3);
    const int t4 = a * 2 + bb;
    const size_t base = ((size_t)bh * 32 + blk) * 768;

    bf16x8 hs, hw;
    #pragma unroll
    for (int i = 0; i < 8; ++i) { hs[i] = f2bf(s8[i]); hw[i] = f2bf(w8[i]); }
    *(bf16x8*)(KV + (base + (t4 * 2 + 0) * 64 + part * 16 + lo) * 8) = hs;
    *(bf16x8*)(KV + (base + (t4 * 2 + 1) * 64 + part * 16 + lo) * 8) = hw;

    __syncthreads();

    {
      const int j = t >> 6, l = t & 63;
      const int dt = j >> 1, kw = j & 1;
      const int lo2 = l & 15, quad = l >> 4;
      const int d = dt * 16 + lo2;
      bf16x8 hv;
      #pragma unroll
      for (int i = 0; i < 8; ++i)
        hv[i] = f2bf(ldsv[kw * 32 + quad * 8 + i][d]);
      *(bf16x8*)(KV + (base + 512 + t) * 8) = hv;
    }

  } else {
    // ---------------- Wo -> bf16 hi/lo split ----------------
    const int i = ((bid - PREP_W0) * 256 + t) * 4;
    const f32x4 v = *(const f32x4*)(Wo + i);
    s16x4 h, l;
    #pragma unroll
    for (int j = 0; j < 4; ++j) {
      h[j] = f2bf(v[j]);
      l[j] = f2bf(v[j] - bf2f(h[j]));
    }
    *(s16x4*)(WoH + i) = h;
    *(s16x4*)(WoL + i) = l;
  }
}

// ---------------------------------------------------------------------------
// Flash attention: 32 q per wave (2 q-tiles share K/V LDS fragments),
// LDS double buffer via global_load_lds, log-free softmax, l via MFMA
// ones-row, SPLIT=4, XCD-swizzled 1-D grid, bf16 fragment-ordered pi.
// ---------------------------------------------------------------------------
union PF { int i[4]; bf16x8 v; };

__device__ __forceinline__ void attn_step2(
    const short* __restrict__ cbuf, const bf16x8 qh[2][2],
    const short* __restrict__ pit0, const short* __restrict__ pit1,
    const float* __restrict__ kbp, const bf16x8 ones, int lane,
    float m[2], f32x4 o[2][2], f32x4 ol[2])
{
  // pi (bf16, coalesced fragment order) + kb (quad-broadcast), issued first
  bf16x8 pg[2][2];
  pg[0][0] = *(const bf16x8*)(pit0);
  pg[0][1] = *(const bf16x8*)(pit0 + 512);
  pg[1][0] = *(const bf16x8*)(pit1);
  pg[1][1] = *(const bf16x8*)(pit1 + 512);
  f32x4 kb4[4];
  kb4[0] = *(const f32x4*)(kbp);
  kb4[1] = *(const f32x4*)(kbp + 4);
  kb4[2] = *(const f32x4*)(kbp + 32);
  kb4[3] = *(const f32x4*)(kbp + 36);

  // QK^T: K fragments shared by both q-tiles
  f32x4 st[2][4];
  #pragma unroll
  for (int t4 = 0; t4 < 4; ++t4) {
    const bf16x8 ka0 = *(const bf16x8*)(cbuf + ((t4 * 2 + 0) * 64 + lane) * 8);
    const bf16x8 ka1 = *(const bf16x8*)(cbuf + ((t4 * 2 + 1) * 64 + lane) * 8);
    #pragma unroll
    for (int tl = 0; tl < 2; ++tl) {
      f32x4 z = {0.f, 0.f, 0.f, 0.f};
      z = __builtin_amdgcn_mfma_f32_16x16x32_bf16(ka0, qh[tl][0], z, 0, 0, 0);
      z = __builtin_amdgcn_mfma_f32_16x16x32_bf16(ka1, qh[tl][1], z, 0, 0, 0);
      st[tl][t4] = z;
    }
  }

  // V fragments shared by both q-tiles
  const bf16x8 va00 = *(const bf16x8*)(cbuf + ((512 + 0 * 64) + lane) * 8);
  const bf16x8 va01 = *(const bf16x8*)(cbuf + ((512 + 1 * 64) + lane) * 8);
  const bf16x8 va10 = *(const bf16x8*)(cbuf + ((512 + 2 * 64) + lane) * 8);
  const bf16x8 va11 = *(const bf16x8*)(cbuf + ((512 + 3 * 64) + lane) * 8);

  #pragma unroll
  for (int tl = 0; tl < 2; ++tl) {
    float lg[16];
    #pragma unroll
    for (int t4 = 0; t4 < 4; ++t4) {
      #pragma unroll
      for (int r = 0; r < 4; ++r) lg[t4 * 4 + r] = st[tl][t4][r] + kb4[t4][r];
    }

    float cm = lg[0];
    #pragma unroll
    for (int j = 1; j < 16; ++j) cm = fmaxf(cm, lg[j]);
    cm = fmaxf(cm, __shfl_xor(cm, 16));
    cm = fmaxf(cm, __shfl_xor(cm, 32));
    const float mn = fmaxf(m[tl], cm);
    const float sc = __builtin_amdgcn_exp2f(m[tl] - mn);
    m[tl] = mn;

    unsigned eu[16];
    #pragma unroll
    for (int j = 0; j < 16; ++j) {
      const float pif = bf2f(pg[tl][j >> 3][j & 7]);
      eu[j] = __float_as_uint(__builtin_amdgcn_exp2f(lg[j] - mn) * pif);
    }

    PF pf0, pf1;
    #pragma unroll
    for (int p = 0; p < 4; ++p) {
      pf0.i[p] = __builtin_amdgcn_perm(eu[2 * p + 1], eu[2 * p], 0x07060302u);
      pf1.i[p] = __builtin_amdgcn_perm(eu[8 + 2 * p + 1], eu[8 + 2 * p], 0x07060302u);
    }

    #pragma unroll
    for (int r = 0; r < 4; ++r) { o[tl][0][r] *= sc; o[tl][1][r] *= sc; ol[tl][r] *= sc; }

    o[tl][0] = __builtin_amdgcn_mfma_f32_16x16x32_bf16(va00, pf0.v, o[tl][0], 0, 0, 0);
    o[tl][0] = __builtin_amdgcn_mfma_f32_16x16x32_bf16(va01, pf1.v, o[tl][0], 0, 0, 0);
    o[tl][1] = __builtin_amdgcn_mfma_f32_16x16x32_bf16(va10, pf0.v, o[tl][1], 0, 0, 0);
    o[tl][1] = __builtin_amdgcn_mfma_f32_16x16x32_bf16(va11, pf1.v, o[tl][1], 0, 0, 0);
    // l accumulation on the matrix pipe: row-0 ones A-operand
    ol[tl] = __builtin_amdgcn_mfma_f32_16x16x32_bf16(ones, pf0.v, ol[tl], 0, 0, 0);
    ol[tl] = __builtin_amdgcn_mfma_f32_16x16x32_bf16(ones, pf1.v, ol[tl], 0, 0, 0);
  }
}

__global__ __launch_bounds__(256, 4) void attn_kernel(
    const short* __restrict__ Qh, const short* __restrict__ KV,
    const float* __restrict__ kb, const short* __restrict__ piB,
    float* __restrict__ part)
{
  __shared__ short skv[2][6144];   // 2 x 768 granules x 16 B
  // XCD swizzle: 8 q-blocks sharing (bh,sp) land on one XCD
  const int id = blockIdx.x;
  const int combo = id & 127;      // (bh<<2) | sp
  const int qblk  = id >> 7;       // 0..7
  const int bh = combo >> 2;
  const int sp = combo & 3;
  const int b = bh >> 3;
  const int wv = threadIdx.x >> 6;
  const int lane = threadIdx.x & 63;
  const int lo16 = lane & 15;
  const int quad = lane >> 4;
  const int qt0 = qblk * 8 + wv * 2;   // first of two q-tiles
  const int blk0 = sp * ITERS;

  bf16x8 qh[2][2];
  #pragma unroll
  for (int tl = 0; tl < 2; ++tl) {
    const size_t qoff = ((size_t)bh * LQ + (qt0 + tl) * 16 + lo16) * 64 + quad * 8;
    qh[tl][0] = *(const bf16x8*)(Qh + qoff);
    qh[tl][1] = *(const bf16x8*)(Qh + qoff + 32);
  }

  const short* pit0 = piB + ((((size_t)(b * 64 + qt0) * 32) + blk0) * 128 + lane) * 8;
  const short* pit1 = piB + ((((size_t)(b * 64 + qt0 + 1) * 32) + blk0) * 128 + lane) * 8;
  const float* kbbase = kb + (size_t)bh * LK + sp * KPS + quad * 8;

  bf16x8 ones;
  #pragma unroll
  for (int j = 0; j < 8; ++j) ones[j] = (lo16 == 0) ? (short)0x3F80 : (short)0;

  float m[2] = {-1e30f, -1e30f};
  f32x4 o[2][2] = {{{0.f,0.f,0.f,0.f},{0.f,0.f,0.f,0.f}},
                   {{0.f,0.f,0.f,0.f},{0.f,0.f,0.f,0.f}}};
  f32x4 ol[2] = {{0.f,0.f,0.f,0.f},{0.f,0.f,0.f,0.f}};

  // prologue: DMA buffer 0
  {
    const size_t gb = ((size_t)bh * 32 + blk0) * 768;
    #pragma unroll
    for (int c = 0; c < 3; ++c)
      gl_lds16(KV + (gb + c * 256 + wv * 64 + lane) * 8,
               &skv[0][c * 2048 + wv * 512]);
  }

  for (int it = 0; it < ITERS; it += 2) {
    __syncthreads();   // DMA for buffer0 (it) complete
    {
      const size_t gb = ((size_t)bh * 32 + blk0 + it + 1) * 768;
      #pragma unroll
      for (int c = 0; c < 3; ++c)
        gl_lds16(KV + (gb + c * 256 + wv * 64 + lane) * 8,
                 &skv[1][c * 2048 + wv * 512]);
    }
    attn_step2(skv[0], qh, pit0 + it * 1024, pit1 + it * 1024,
               kbbase + it * 64, ones, lane, m, o, ol);

    __syncthreads();   // DMA for buffer1 (it+1) complete
    if (it + 2 < ITERS) {
      const size_t gb = ((size_t)bh * 32 + blk0 + it + 2) * 768;
      #pragma unroll
      for (int c = 0; c < 3; ++c)
        gl_lds16(KV + (gb + c * 256 + wv * 64 + lane) * 8,
                 &skv[0][c * 2048 + wv * 512]);
    }
    attn_step2(skv[1], qh, pit0 + (it + 1) * 1024, pit1 + (it + 1) * 1024,
               kbbase + (it + 1) * 64, ones, lane, m, o, ol);
  }

  // partial out: [sp][bh][q] stride 36 floats: m, l, _, _, o[32]
  #pragma unroll
  for (int tl = 0; tl < 2; ++tl) {
    const int q = (qt0 + tl) * 16 + lo16;
    float* ppart = part + ((size_t)(sp * 32 + bh) * LQ + q) * 36;
    if (quad == 0) { ppart[0] = m[tl]; ppart[1] = ol[tl][0]; }
    *(f32x4*)(ppart + 4 + quad * 4)  = o[tl][0];
    *(f32x4*)(ppart + 20 + quad * 4) = o[tl][1];
  }
}

// ---------------------------------------------------------------------------
// Fused combine (4-way) + output GEMM via MFMA (hi/lo bf16 compensation).
// Stage 1: cooperative A-build; Stage 2: GEMM with A from LDS.
// ---------------------------------------------------------------------------
__global__ __launch_bounds__(256) void out_kernel(
    const float* __restrict__ part, const short* __restrict__ WoH,
    const short* __restrict__ WoL, const float* __restrict__ bo,
    float* __restrict__ out)
{
  __shared__ short lA[2][8 * 64 * 8];   // [hi/lo][(win*64+lane)*8]
  const int t = threadIdx.x;
  const int mt = blockIdx.x;            // m-tile of 16 rows

  // ---- stage 1: cooperative A-build ----
  {
    const int win = t >> 5;             // 0..7
    const int row = (t >> 1) & 15;      // 0..15
    const int qp  = t & 1;              // quads {0,1} or {2,3}
    const size_t gq = (size_t)mt * 16 + row;
    const int b = (int)(gq >> 10), qq = (int)(gq & (LQ - 1));
    const size_t r = (size_t)(b * H_ + win) * LQ + qq;

    const float* p[SPLIT];
    float ms[SPLIT], ls[SPLIT];
    #pragma unroll
    for (int s = 0; s < SPLIT; ++s) {
      p[s] = part + (r + (size_t)s * (B_ * H_ * LQ)) * 36;
      ms[s] = p[s][0]; ls[s] = p[s][1];
    }
    float mM = ms[0];
    #pragma unroll
    for (int s = 1; s < SPLIT; ++s) mM = fmaxf(mM, ms[s]);
    float ws[SPLIT], den = 0.f;
    #pragma unroll
    for (int s = 0; s < SPLIT; ++s) {
      ws[s] = __builtin_amdgcn_exp2f(ms[s] - mM);
      den += ws[s] * ls[s];
    }
    const float inv = 1.f / den;

    #pragma unroll
    for (int q2 = 0; q2 < 2; ++q2) {
      const int quad = qp * 2 + q2;
      float c8[8];
      #pragma unroll
      for (int j = 0; j < 8; ++j) c8[j] = 0.f;
      #pragma unroll
      for (int s = 0; s < SPLIT; ++s) {
        const f32x4 a0 = *(const f32x4*)(p[s] + 4 + quad * 8);
        const f32x4 a1 = *(const f32x4*)(p[s] + 8 + quad * 8);
        #pragma unroll
        for (int j = 0; j < 4; ++j) {
          c8[j]     += ws[s] * a0[j];
          c8[4 + j] += ws[s] * a1[j];
        }
      }
      bf16x8 ah, al;
      #pragma unroll
      for (int j = 0; j < 8; ++j) {
        const float cv = c8[j] * inv;
        const short hi = f2bf(cv);
        ah[j] = hi;
        al[j] = f2bf(cv - bf2f(hi));
      }
      const int gidx = (win * 64 + quad * 16 + row) * 8;
      *(bf16x8*)(&lA[0][gidx]) = ah;
      *(bf16x8*)(&lA[1][gidx]) = al;
    }
  }
  __syncthreads();

  // ---- stage 2: GEMM ----
  const int wv = t >> 6, lane = t & 63;
  const int lo16 = lane & 15, quad = lane >> 4;

  bf16x8 Ah[8], Al[8];
  #pragma unroll
  for (int win = 0; win < 8; ++win) {
    Ah[win] = *(const bf16x8*)(&lA[0][(win * 64 + lane) * 8]);
    Al[win] = *(const bf16x8*)(&lA[1][(win * 64 + lane) * 8]);
  }

  const int n0 = wv * 64;
  #pragma unroll
  for (int nt = 0; nt < 4; ++nt) {
    const int nb = n0 + nt * 16;
    const short* bh = WoH + (size_t)(nb + lo16) * HID_ + quad * 8;
    const short* bl = WoL + (size_t)(nb + lo16) * HID_ + quad * 8;
    const float bias = bo[nb + lo16];
    f32x4 acc = {bias, bias, bias, bias};
    #pragma unroll
    for (int win = 0; win < 8; ++win) {
      const bf16x8 Bh = *(const bf16x8*)(bh + win * 32);
      const bf16x8 Bl = *(const bf16x8*)(bl + win * 32);
      acc = __builtin_amdgcn_mfma_f32_16x16x32_bf16(Ah[win], Bh, acc, 0, 0, 0);
      acc = __builtin_amdgcn_mfma_f32_16x16x32_bf16(Al[win], Bh, acc, 0, 0, 0);
      acc = __builtin_amdgcn_mfma_f32_16x16x32_bf16(Ah[win], Bl, acc, 0, 0, 0);
    }
    #pragma unroll
    for (int r4 = 0; r4 < 4; ++r4)
      out[(size_t)(mt * 16 + quad * 4 + r4) * HID_ + nb + lo16] = acc[r4];
  }
}

// ---------------------------------------------------------------------------
extern "C" void kernel_launch(void* const* d_in, const int* in_sizes, int n_in,
                              void* d_out, int out_size, void* d_ws, size_t ws_size,
                              hipStream_t stream)
{
  const float* q_fp  = (const float*)d_in[0];
  const float* v_ret = (const float*)d_in[1];
  const float* pi    = (const float*)d_in[2];
  const float* Wq_s  = (const float*)d_in[3];
  const float* bq_s  = (const float*)d_in[4];
  const float* Wk_s  = (const float*)d_in[5];
  const float* bk_s  = (const float*)d_in[6];
  const float* Wq_w  = (const float*)d_in[7];
  const float* bq_w  = (const float*)d_in[8];
  const float* Wk_w  = (const float*)d_in[9];
  const float* bk_w  = (const float*)d_in[10];
  const float* Wv    = (const float*)d_in[11];
  const float* bv    = (const float*)d_in[12];
  const float* Wo    = (const float*)d_in[13];
  const float* bo    = (const float*)d_in[14];
  const float* wb    = (const float*)d_in[15];
  float* out = (float*)d_out;

  // ws: Qh 4MB | KV 12MB | kb 256KB | piB 16.8MB | part 18.9MB | WoH/L 256KB
  short* Qh   = (short*)d_ws;                     // 2,097,152 sh
  short* KV   = Qh + (size_t)2097152;             // 6,291,456 sh
  float* kbuf = (float*)(KV + (size_t)6291456);   //    65,536 fl
  short* piB  = (short*)(kbuf + (size_t)65536);   // 8,388,608 sh
  float* part = (float*)(piB + (size_t)8388608);  // 4,718,592 fl
  short* WoH  = (short*)(part + (size_t)4718592); //    65,536 sh
  short* WoL  = WoH + (size_t)65536;              //    65,536 sh

  prep_kernel<<<PREP_NBLK, 256, 0, stream>>>(
      q_fp, v_ret, pi, Wq_s, bq_s, Wq_w, bq_w, Wk_s, bk_s, Wk_w, bk_w,
      Wv, bv, Wo, wb, Qh, KV, kbuf, piB, WoH, WoL);
  attn_kernel<<<(LQ / 128) * 32 * SPLIT, 256, 0, stream>>>(Qh, KV, kbuf, piB, part);
  out_kernel<<<(B_ * LQ) / 16, 256, 0, stream>>>(part, WoH, WoL, bo, out);
}